// Round 7
// baseline (189.825 us; speedup 1.0000x reference)
//
#include <hip/hip_runtime.h>
#include <math.h>

#define N_ROWS 8192
#define DIM 512
#define HID 1024
#define NSPLIT 16
#define SPLITC 512
#define NCT 4

typedef _Float16 f16x8 __attribute__((ext_vector_type(8)));
typedef _Float16 f16x4 __attribute__((ext_vector_type(4)));
typedef float f32x4 __attribute__((ext_vector_type(4)));

__device__ __forceinline__ bool dj_less(float d1, int j1, float d2, int j2) {
  return (d1 < d2) || (d1 == d2 && j1 < j2);
}
__device__ __forceinline__ unsigned umin32(unsigned a, unsigned b) { return a < b ? a : b; }
__device__ __forceinline__ unsigned umax32(unsigned a, unsigned b) { return a > b ? a : b; }

__device__ __forceinline__ void gload_lds16(const void* g, void* s) {
  __builtin_amdgcn_global_load_lds((const __attribute__((address_space(1))) void*)g,
                                   (__attribute__((address_space(3))) void*)s, 16, 0, 0);
}

#define S_SWZ(r) ((((r) & 3) ^ (((r) >> 2) & 3)))

// branchless sorted-insert of x into ascending K[0..3]
#define INS4(K, xin)                                   \
  {                                                    \
    unsigned xx = (xin), t;                            \
    t = umin32(K[0], xx); xx = umax32(K[0], xx); K[0] = t; \
    t = umin32(K[1], xx); xx = umax32(K[1], xx); K[1] = t; \
    t = umin32(K[2], xx); xx = umax32(K[2], xx); K[2] = t; \
    K[3] = umin32(K[3], xx);                           \
  }

// ---------------- fused converts: x->f16 + row sq-norms, W1->f16, W2->f16 ----------------
__global__ __launch_bounds__(256) void convert_kernel(const float* __restrict__ x,
                                                      const float* __restrict__ W1,
                                                      const float* __restrict__ W2,
                                                      _Float16* __restrict__ xh,
                                                      _Float16* __restrict__ W1f,
                                                      _Float16* __restrict__ W2f,
                                                      float* __restrict__ sq) {
  int bid = blockIdx.x;
  int tid = threadIdx.x;
  if (bid < 4096) {
    int g = bid * 256 + tid;
    float4 v = reinterpret_cast<const float4*>(x)[g];
    f16x4 hv = {(_Float16)v.x, (_Float16)v.y, (_Float16)v.z, (_Float16)v.w};
    reinterpret_cast<f16x4*>(xh)[g] = hv;
    float s = v.x * v.x + v.y * v.y + v.z * v.z + v.w * v.w;
    for (int off = 32; off > 0; off >>= 1) s += __shfl_down(s, off);
    __shared__ float red[4];
    if ((tid & 63) == 0) red[tid >> 6] = s;
    __syncthreads();
    if (tid == 0) sq[bid * 2] = red[0] + red[1];
    if (tid == 128) sq[bid * 2 + 1] = red[2] + red[3];
  } else {
    const float* src = (bid < 5120) ? W1 : W2;
    _Float16* dst = (bid < 5120) ? W1f : W2f;
    int g = ((bid < 5120) ? (bid - 4096) : (bid - 5120)) * 256 + tid;
    float4 v = reinterpret_cast<const float4*>(src)[g];
    f16x4 h = {(_Float16)v.x, (_Float16)v.y, (_Float16)v.z, (_Float16)v.w};
    reinterpret_cast<f16x4*>(dst)[g] = h;
  }
}

// ---------------- f16 MFMA distance + per-row candidate keys (16 j-splits) ----------------
// grid (64, 16), block 256 (4 waves 2x2). Tile 128x128, BK=32, double-buffered staging.
// Dk key planes alias buf1 (epilogue-only lifetime) -> LDS 34816 B -> 4 blocks/CU.
// key = (bits(d~ + 1024) & 0xFFFFE000) | col
__global__ __launch_bounds__(256, 4) void dist_cand_mfma(const _Float16* __restrict__ xh,
                                                         const float* __restrict__ sq,
                                                         unsigned int* __restrict__ cand) {
  // LDS: buf0 [0,16K) buf1 [16K,32K); DkA [64][36] @16384 (over buf1), DkB @25600, end 34816
  __shared__ __align__(16) char smem[34816];
  unsigned* DkA = (unsigned*)(smem + 16384);
  unsigned* DkB = (unsigned*)(smem + 25600);
  const int tid = threadIdx.x;
  const int lane = tid & 63;
  const int w = tid >> 6;
  const int wm = w >> 1, wn = w & 1;
  const int row0 = blockIdx.x * 128;
  const int js = blockIdx.y;

  int a_off[4], b_off[4];
#pragma unroll
  for (int m = 0; m < 4; ++m) {
    int r = wm * 64 + m * 16 + (lane & 15);
    a_off[m] = r * 64 + (((lane >> 4) ^ S_SWZ(r)) * 16);
  }
#pragma unroll
  for (int n = 0; n < 4; ++n) {
    int r = wn * 64 + n * 16 + (lane & 15);
    b_off[n] = r * 64 + (((lane >> 4) ^ S_SWZ(r)) * 16);
  }

  int goff[2], wb[2];
#pragma unroll
  for (int h = 0; h < 2; ++h) {
    int i = h * 256 + tid;
    int r = i >> 2, cs = i & 3;
    int c = cs ^ S_SWZ(r);
    goff[h] = r * 512 + c * 8;   // f16 elements
    wb[h] = h * 4096 + w * 1024; // bytes, wave-uniform
  }

  const int sr = tid >> 2;  // scan row 0..63
  const int sc = tid & 3;   // scan class 0..3
  const int slot = wn * 16 + (lane & 15);

  unsigned keys[2][4];
#pragma unroll
  for (int p = 0; p < 2; ++p)
#pragma unroll
    for (int q = 0; q < 4; ++q) keys[p][q] = 0xFFFFFFFFu;

  const _Float16* arow = xh + (size_t)row0 * DIM;

  f32x4 acc[4][4];

  auto stage = [&](int b, const _Float16* br, int kt) {
#pragma unroll
    for (int h = 0; h < 2; ++h) {
      int go = goff[h] + kt * 32;
      gload_lds16(arow + go, smem + b * 16384 + wb[h]);
      gload_lds16(br + go, smem + b * 16384 + 8192 + wb[h]);
    }
  };
  auto compute = [&](int b) {
    f16x8 bf[4];
#pragma unroll
    for (int n = 0; n < 4; ++n) bf[n] = *(const f16x8*)(smem + b * 16384 + 8192 + b_off[n]);
#pragma unroll
    for (int m = 0; m < 4; ++m) {
      f16x8 af = *(const f16x8*)(smem + b * 16384 + a_off[m]);
#pragma unroll
      for (int n = 0; n < 4; ++n)
        acc[m][n] = __builtin_amdgcn_mfma_f32_16x16x32_f16(af, bf[n], acc[m][n], 0, 0, 0);
    }
  };

  // prologue: stage ct=0, kt=0 into buf0
  stage(0, xh + (size_t)(js * SPLITC) * DIM, 0);
  __syncthreads();

#pragma unroll 1
  for (int ct = 0; ct < NCT; ++ct) {
    const int c0 = js * SPLITC + ct * 128;
    const _Float16* brow = xh + (size_t)c0 * DIM;
#pragma unroll
    for (int m = 0; m < 4; ++m)
#pragma unroll
      for (int n = 0; n < 4; ++n) acc[m][n] = (f32x4)0.0f;

#pragma unroll 1
    for (int k = 0; k < 8; ++k) {
      stage(1, brow, 2 * k + 1);
      compute(0);
      __syncthreads();
      if (k < 7) stage(0, brow, 2 * k + 2);
      compute(1);
      __syncthreads();
    }

    // prefetch next ct's kt=0 into buf0 (drained by epilogue barriers)
    stage(0, xh + (size_t)(js * SPLITC + ((ct + 1) & (NCT - 1)) * 128) * DIM, 0);

    float sqjb[4];
#pragma unroll
    for (int n = 0; n < 4; ++n) sqjb[n] = sq[c0 + wn * 64 + n * 16 + (lane & 15)] + 1024.0f;

#pragma unroll
    for (int p = 0; p < 2; ++p) {
      if (wm == p) {
#pragma unroll
        for (int m = 0; m < 4; ++m)
#pragma unroll
          for (int j = 0; j < 4; ++j) {
            int rl = m * 16 + ((lane >> 4) << 2) + j;
            unsigned u[4];
#pragma unroll
            for (int n = 0; n < 4; ++n) {
              float v = fmaf(-2.0f, acc[m][n][j], sqjb[n]);
              u[n] = (__float_as_uint(v) & 0xFFFFE000u) |
                     (unsigned)(c0 + wn * 64 + n * 16 + (lane & 15));
            }
            unsigned lo01 = umin32(u[0], u[1]), hi01 = umax32(u[0], u[1]);
            unsigned lo23 = umin32(u[2], u[3]), hi23 = umax32(u[2], u[3]);
            DkA[rl * 36 + slot] = umin32(lo01, lo23);
            DkB[rl * 36 + slot] = umin32(umax32(lo01, lo23), umin32(hi01, hi23));
          }
      }
      __syncthreads();
      {
        const uint4* pa = (const uint4*)&DkA[sr * 36 + sc * 8];
        const uint4* pb = (const uint4*)&DkB[sr * 36 + sc * 8];
        uint4 a0 = pa[0], a1 = pa[1], b0 = pb[0], b1 = pb[1];
        INS4(keys[p], a0.x); INS4(keys[p], a0.y); INS4(keys[p], a0.z); INS4(keys[p], a0.w);
        INS4(keys[p], a1.x); INS4(keys[p], a1.y); INS4(keys[p], a1.z); INS4(keys[p], a1.w);
        INS4(keys[p], b0.x); INS4(keys[p], b0.y); INS4(keys[p], b0.z); INS4(keys[p], b0.w);
        INS4(keys[p], b1.x); INS4(keys[p], b1.y); INS4(keys[p], b1.z); INS4(keys[p], b1.w);
      }
      __syncthreads();
    }
  }

  // write candidates: 4 sorted keys per (row, scan-class) per split
#pragma unroll
  for (int p = 0; p < 2; ++p) {
    int row = row0 + p * 64 + sr;
    uint4 o;
    o.x = keys[p][0]; o.y = keys[p][1]; o.z = keys[p][2]; o.w = keys[p][3];
    *reinterpret_cast<uint4*>(&cand[(size_t)row * 256 + js * 16 + sc * 4]) = o;
  }
}

// ---------------- rescore + pool: 4 rows/block, one wave per row ----------------
__global__ __launch_bounds__(256) void rescore_pool_kernel(const float* __restrict__ x,
                                                           const float* __restrict__ sq,
                                                           const unsigned int* __restrict__ cand,
                                                           float* __restrict__ orows,
                                                           float* __restrict__ osubs,
                                                           _Float16* __restrict__ h0) {
  const int lane = threadIdx.x & 63;
  const int wid = threadIdx.x >> 6;
  const int row = blockIdx.x * 4 + wid;
  uint4 q = *reinterpret_cast<const uint4*>(&cand[(size_t)row * 256 + lane * 4]);
  unsigned cur = q.x, c1 = q.y, c2 = q.z, c3 = q.w;
  unsigned myj = 0;
#pragma unroll 1
  for (int r = 0; r < 16; ++r) {
    unsigned mn = cur;
#pragma unroll
    for (int off = 32; off > 0; off >>= 1)
      mn = umin32(mn, (unsigned)__shfl_xor((int)mn, off));
    if (cur == mn) { cur = c1; c1 = c2; c2 = c3; c3 = 0xFFFFFFFFu; }
    if (lane == r) myj = mn & 0x1FFFu;
  }

  const float4* xi = reinterpret_cast<const float4*>(x + (size_t)row * DIM);
  float4 xa = xi[lane];
  float4 xb = xi[lane + 64];
  float sqi = sq[row];

  float dme = 0.0f;
  int jme = 0;
#pragma unroll 1
  for (int c = 0; c < 16; ++c) {
    int j = __shfl((int)myj, c);
    const float4* xj = reinterpret_cast<const float4*>(x + (size_t)j * DIM);
    float4 ya = xj[lane];
    float4 yb = xj[lane + 64];
    float dot = xa.x * ya.x + xa.y * ya.y + xa.z * ya.z + xa.w * ya.w +
                xb.x * yb.x + xb.y * yb.y + xb.z * yb.z + xb.w * yb.w;
#pragma unroll
    for (int off = 32; off > 0; off >>= 1) dot += __shfl_xor(dot, off);
    float d = sqi + sq[j] - 2.0f * dot;
    if (lane == c) { dme = d; jme = j; }
  }

  int rank2 = 0;
#pragma unroll
  for (int k = 0; k < 16; ++k) {
    float dk = __shfl(dme, k);
    int jk = __shfl(jme, k);
    rank2 += dj_less(dk, jk, dme, jme) ? 1 : 0;
  }
  __shared__ int s4[4][4];
  if (lane < 16 && rank2 < 4) {
    s4[wid][rank2] = jme;
    orows[row * 4 + rank2] = (float)row;
    osubs[row * 4 + rank2] = (float)jme;
  }
  __syncthreads();

  // pooling: 8 cols per lane over the 4 selected rows
  int j0 = s4[wid][0], j1 = s4[wid][1], j2 = s4[wid][2], j3 = s4[wid][3];
  int c = lane * 8;
  float4 z0a = *reinterpret_cast<const float4*>(&x[(size_t)j0 * DIM + c]);
  float4 z0b = *reinterpret_cast<const float4*>(&x[(size_t)j0 * DIM + c + 4]);
  float4 z1a = *reinterpret_cast<const float4*>(&x[(size_t)j1 * DIM + c]);
  float4 z1b = *reinterpret_cast<const float4*>(&x[(size_t)j1 * DIM + c + 4]);
  float4 z2a = *reinterpret_cast<const float4*>(&x[(size_t)j2 * DIM + c]);
  float4 z2b = *reinterpret_cast<const float4*>(&x[(size_t)j2 * DIM + c + 4]);
  float4 z3a = *reinterpret_cast<const float4*>(&x[(size_t)j3 * DIM + c]);
  float4 z3b = *reinterpret_cast<const float4*>(&x[(size_t)j3 * DIM + c + 4]);
  f16x8 mu, mx;
  mu[0] = (_Float16)((z0a.x + z1a.x + z2a.x + z3a.x) * 0.25f);
  mu[1] = (_Float16)((z0a.y + z1a.y + z2a.y + z3a.y) * 0.25f);
  mu[2] = (_Float16)((z0a.z + z1a.z + z2a.z + z3a.z) * 0.25f);
  mu[3] = (_Float16)((z0a.w + z1a.w + z2a.w + z3a.w) * 0.25f);
  mu[4] = (_Float16)((z0b.x + z1b.x + z2b.x + z3b.x) * 0.25f);
  mu[5] = (_Float16)((z0b.y + z1b.y + z2b.y + z3b.y) * 0.25f);
  mu[6] = (_Float16)((z0b.z + z1b.z + z2b.z + z3b.z) * 0.25f);
  mu[7] = (_Float16)((z0b.w + z1b.w + z2b.w + z3b.w) * 0.25f);
  mx[0] = (_Float16)fmaxf(fmaxf(z0a.x, z1a.x), fmaxf(z2a.x, z3a.x));
  mx[1] = (_Float16)fmaxf(fmaxf(z0a.y, z1a.y), fmaxf(z2a.y, z3a.y));
  mx[2] = (_Float16)fmaxf(fmaxf(z0a.z, z1a.z), fmaxf(z2a.z, z3a.z));
  mx[3] = (_Float16)fmaxf(fmaxf(z0a.w, z1a.w), fmaxf(z2a.w, z3a.w));
  mx[4] = (_Float16)fmaxf(fmaxf(z0b.x, z1b.x), fmaxf(z2b.x, z3b.x));
  mx[5] = (_Float16)fmaxf(fmaxf(z0b.y, z1b.y), fmaxf(z2b.y, z3b.y));
  mx[6] = (_Float16)fmaxf(fmaxf(z0b.z, z1b.z), fmaxf(z2b.z, z3b.z));
  mx[7] = (_Float16)fmaxf(fmaxf(z0b.w, z1b.w), fmaxf(z2b.w, z3b.w));
  *reinterpret_cast<f16x8*>(&h0[(size_t)row * HID + c]) = mu;
  *reinterpret_cast<f16x8*>(&h0[(size_t)row * HID + DIM + c]) = mx;
}

// ---------------- f16 MFMA GEMM, 8 waves (4x2), wave tile 32x64, double-buffered ----------------
// out16 = act(A @ W^T + bias).  A (8192 x 1024 f16), W (1024 x 1024 f16).  grid (64, 8).
__global__ __launch_bounds__(512, 2) void gemm_mfma_kernel(const _Float16* __restrict__ A,
                                                           const _Float16* __restrict__ W,
                                                           const float* __restrict__ bias,
                                                           _Float16* __restrict__ out16,
                                                           int act) {
  __shared__ __align__(16) char smem[32768];  // 2 buffers x (A 8K + B 8K)
  const int tid = threadIdx.x;
  const int lane = tid & 63;
  const int w = tid >> 6;        // 0..7
  const int wm = w >> 1;         // 0..3 (row quarter)
  const int wn = w & 1;          // 0..1 (col half)
  const int row0 = blockIdx.x * 128;
  const int col0 = blockIdx.y * 128;

  int a_off[2], b_off[4];
#pragma unroll
  for (int m = 0; m < 2; ++m) {
    int r = wm * 32 + m * 16 + (lane & 15);
    a_off[m] = r * 64 + (((lane >> 4) ^ S_SWZ(r)) * 16);
  }
#pragma unroll
  for (int n = 0; n < 4; ++n) {
    int r = wn * 64 + n * 16 + (lane & 15);
    b_off[n] = r * 64 + (((lane >> 4) ^ S_SWZ(r)) * 16);
  }

  // staging: 512 threads x 1 chunk of 16B per tensor tile
  int sgr = tid >> 2, scs = tid & 3;
  int sgc = scs ^ S_SWZ(sgr);
  int goff = sgr * HID + sgc * 8;  // f16 elements (row stride K=1024)
  int wb = w * 1024;               // bytes, wave-uniform

  const _Float16* arow = A + (size_t)row0 * HID;
  const _Float16* brow = W + (size_t)col0 * HID;

  f32x4 acc[2][4];
#pragma unroll
  for (int m = 0; m < 2; ++m)
#pragma unroll
    for (int n = 0; n < 4; ++n) acc[m][n] = (f32x4)0.0f;

  auto stage = [&](int b, int kt) {
    int go = goff + kt * 32;
    gload_lds16(arow + go, smem + b * 16384 + wb);
    gload_lds16(brow + go, smem + b * 16384 + 8192 + wb);
  };
  auto compute = [&](int b) {
    f16x8 bf[4];
#pragma unroll
    for (int n = 0; n < 4; ++n) bf[n] = *(const f16x8*)(smem + b * 16384 + 8192 + b_off[n]);
#pragma unroll
    for (int m = 0; m < 2; ++m) {
      f16x8 af = *(const f16x8*)(smem + b * 16384 + a_off[m]);
#pragma unroll
      for (int n = 0; n < 4; ++n)
        acc[m][n] = __builtin_amdgcn_mfma_f32_16x16x32_f16(af, bf[n], acc[m][n], 0, 0, 0);
    }
  };

  stage(0, 0);
  __syncthreads();
#pragma unroll 1
  for (int k = 0; k < 16; ++k) {
    stage(1, 2 * k + 1);
    compute(0);
    __syncthreads();
    if (k < 15) stage(0, 2 * k + 2);
    compute(1);
    __syncthreads();
  }

  float bv[4];
#pragma unroll
  for (int n = 0; n < 4; ++n) bv[n] = bias[col0 + wn * 64 + n * 16 + (lane & 15)];

#pragma unroll
  for (int m = 0; m < 2; ++m)
#pragma unroll
    for (int n = 0; n < 4; ++n) {
      int cl = col0 + wn * 64 + n * 16 + (lane & 15);
#pragma unroll
      for (int j = 0; j < 4; ++j) {
        int rl = row0 + wm * 32 + m * 16 + ((lane >> 4) << 2) + j;
        float v = acc[m][n][j] + bv[n];
        if (act && v < 0.0f) v *= 0.01f;
        out16[(size_t)rl * HID + cl] = (_Float16)v;
      }
    }
}

// ---------------- final elementwise + entropy partial sums (h2 in f16) ----------------
__global__ __launch_bounds__(256) void outgen_kernel(const float* __restrict__ x,
                                                     const _Float16* __restrict__ h2,
                                                     const float* __restrict__ eps,
                                                     float* __restrict__ xout,
                                                     float* __restrict__ partials) {
  int tid = threadIdx.x;
  int gid = blockIdx.x * 256 + tid;
  size_t base = (size_t)gid * 4;
  int i = (int)(base >> 9);
  int c = (int)(base & 511);
  float4 xv = *reinterpret_cast<const float4*>(&x[base]);
  float4 ev = *reinterpret_cast<const float4*>(&eps[base]);
  f16x4 muh = *reinterpret_cast<const f16x4*>(&h2[(size_t)i * HID + c]);
  f16x4 hsh = *reinterpret_cast<const f16x4*>(&h2[(size_t)i * HID + DIM + c]);
  float hs0 = (float)hsh[0], hs1 = (float)hsh[1], hs2 = (float)hsh[2], hs3 = (float)hsh[3];
  float4 xo;
  xo.x = xv.x + (float)muh[0] + expf(0.5f * hs0) * ev.x;
  xo.y = xv.y + (float)muh[1] + expf(0.5f * hs1) * ev.y;
  xo.z = xv.z + (float)muh[2] + expf(0.5f * hs2) * ev.z;
  xo.w = xv.w + (float)muh[3] + expf(0.5f * hs3) * ev.w;
  *reinterpret_cast<float4*>(&xout[base]) = xo;
  float lsum = hs0 + hs1 + hs2 + hs3;
  for (int off = 32; off > 0; off >>= 1) lsum += __shfl_down(lsum, off);
  __shared__ float red[4];
  if ((tid & 63) == 0) red[tid >> 6] = lsum;
  __syncthreads();
  if (tid == 0) partials[blockIdx.x] = red[0] + red[1] + red[2] + red[3];
}

__global__ __launch_bounds__(256) void entfin_kernel(const float* __restrict__ partials,
                                                     float* __restrict__ ent) {
  int t = threadIdx.x;
  float s = 0.0f;
  for (int q = 0; q < 16; ++q) s += partials[t + 256 * q];
  for (int off = 32; off > 0; off >>= 1) s += __shfl_down(s, off);
  __shared__ float red[4];
  if ((t & 63) == 0) red[t >> 6] = s;
  __syncthreads();
  if (t == 0)
    ent[0] = 0.5f + 0.9189385332046727f +
             0.5f * (red[0] + red[1] + red[2] + red[3]) / (8192.0f * 512.0f);
}

extern "C" void kernel_launch(void* const* d_in, const int* in_sizes, int n_in,
                              void* d_out, int out_size, void* d_ws, size_t ws_size,
                              hipStream_t stream) {
  const float* x = (const float*)d_in[0];
  const float* W1 = (const float*)d_in[1];
  const float* b1 = (const float*)d_in[2];
  const float* W2 = (const float*)d_in[3];
  const float* b2 = (const float*)d_in[4];
  const float* eps = (const float*)d_in[5];

  float* out = (float*)d_out;
  float* ws = (float*)d_ws;

  // workspace layout (float offsets)
  float* sq = ws;                                   // [0, 8192)
  float* partials = ws + 40960;                     // [40960, 45056)
  unsigned int* cand = (unsigned int*)(ws + 65536); // 8192*256 u32 = 8MB (dead after rescore)
  _Float16* h2f = (_Float16*)(ws + 65536);          // 8192*1024 halves, overlaps cand
  _Float16* xh = (_Float16*)(ws + 8454144);         // 8192*512 halves (dead after dist)
  _Float16* h0f = (_Float16*)(ws + 8454144);        // 8192*1024 halves, overlaps xh
  _Float16* h1f = (_Float16*)(ws + 12648448);       // 8192*1024 halves
  _Float16* W1f = (_Float16*)(ws + 16842752);       // 1024*1024 halves
  _Float16* W2f = (_Float16*)(ws + 17367040);       // 1024*1024 halves

  float* xout = out;
  float* ent = out + (size_t)N_ROWS * DIM;
  float* orows = ent + 1;
  float* osubs = orows + (size_t)N_ROWS * 4;

  convert_kernel<<<6144, 256, 0, stream>>>(x, W1, W2, xh, W1f, W2f, sq);
  dist_cand_mfma<<<dim3(64, NSPLIT), 256, 0, stream>>>(xh, sq, cand);
  rescore_pool_kernel<<<N_ROWS / 4, 256, 0, stream>>>(x, sq, cand, orows, osubs, h0f);
  gemm_mfma_kernel<<<dim3(64, 8), 512, 0, stream>>>(h0f, W1f, b1, h1f, 1);
  gemm_mfma_kernel<<<dim3(64, 8), 512, 0, stream>>>(h1f, W2f, b2, h2f, 0);
  outgen_kernel<<<4096, 256, 0, stream>>>(x, h2f, eps, xout, partials);
  entfin_kernel<<<1, 256, 0, stream>>>(partials, ent);
}